// Round 1
// baseline (93.039 us; speedup 1.0000x reference)
//
#include <hip/hip_runtime.h>

#define EPS 1e-7f
#define N256 256
#define NB 64            // n / 4 (float4 chunks per row)
#define BQ 16            // y-rows per block
#define BLOCK 512

__global__ __launch_bounds__(BLOCK, 1)
void cel_kernel(const float* __restrict__ y, const float* __restrict__ A,
                const float* __restrict__ bb, const float* __restrict__ c,
                float* __restrict__ z)
{
    __shared__ float4 ymc[BQ * NB];     // 16 KB: (y - c) tile
    __shared__ float4 c4s[NB];          // 1 KB
    __shared__ float  partial[8][4];    // per-wave row mins
    __shared__ float  alphas[BQ];

    const int t = threadIdx.x;
    const int blk = blockIdx.x;
    const long base4 = (long)blk * (BQ * NB);

    const float4* y4 = (const float4*)y;
    const float4* A4 = (const float4*)A;
    const float4* c4 = (const float4*)c;
    float4* z4 = (float4*)z;

    if (t < NB) c4s[t] = c4[t];

    // stage ymc = y - c (coalesced: global float4 index = base4 + pos is linear in t)
    #pragma unroll
    for (int k = 0; k < (BQ * NB) / BLOCK; ++k) {
        int pos = t + k * BLOCK;
        float4 yv = y4[base4 + pos];
        float4 cv = c4[pos & (NB - 1)];
        float4 r;
        r.x = yv.x - cv.x; r.y = yv.y - cv.y;
        r.z = yv.z - cv.z; r.w = yv.w - cv.w;
        ymc[pos] = r;
    }
    __syncthreads();

    // thread owns A-rows m0, m0+1 and y-rows 4*rg .. 4*rg+3
    const int mg = t & 127;
    const int rg = t >> 7;          // wave-uniform (t>>7 constant within a wave)
    const int m0 = mg * 2;

    float acc[2][4] = {{0.f,0.f,0.f,0.f},{0.f,0.f,0.f,0.f}};
    float accc0 = 0.f, accc1 = 0.f;   // A·c for the two owned rows

    const float4* a0p = A4 + (long)m0 * NB;
    const float4* a1p = a0p + NB;
    const float4* yr  = &ymc[rg * 4 * NB];

    #pragma unroll 4
    for (int n4 = 0; n4 < NB; ++n4) {
        float4 a0 = a0p[n4];
        float4 a1 = a1p[n4];
        float4 cv = c4s[n4];
        accc0 = fmaf(a0.x, cv.x, fmaf(a0.y, cv.y, fmaf(a0.z, cv.z, fmaf(a0.w, cv.w, accc0))));
        accc1 = fmaf(a1.x, cv.x, fmaf(a1.y, cv.y, fmaf(a1.z, cv.z, fmaf(a1.w, cv.w, accc1))));
        #pragma unroll
        for (int j = 0; j < 4; ++j) {
            float4 yv = yr[j * NB + n4];   // LDS broadcast (same addr across lanes)
            acc[0][j] = fmaf(a0.x, yv.x, fmaf(a0.y, yv.y, fmaf(a0.z, yv.z, fmaf(a0.w, yv.w, acc[0][j]))));
            acc[1][j] = fmaf(a1.x, yv.x, fmaf(a1.y, yv.y, fmaf(a1.z, yv.z, fmaf(a1.w, yv.w, acc[1][j]))));
        }
    }

    const float bm0 = bb[m0]     - accc0;
    const float bm1 = bb[m0 + 1] - accc1;

    float val[4];
    #pragma unroll
    for (int j = 0; j < 4; ++j) {
        float ip0 = bm0 / (acc[0][j] + EPS);
        float ip1 = bm1 / (acc[1][j] + EPS);
        float c0 = (ip0 > 1.f || ip0 < 0.f) ? 2.f : ip0;
        float c1 = (ip1 > 1.f || ip1 < 0.f) ? 2.f : ip1;
        val[j] = fminf(c0, c1);
    }

    // wave-level min over 64 lanes (covers 128 m per wave)
    #pragma unroll
    for (int j = 0; j < 4; ++j) {
        float v = val[j];
        #pragma unroll
        for (int off = 1; off < 64; off <<= 1)
            v = fminf(v, __shfl_xor(v, off));
        val[j] = v;
    }

    const int lane = t & 63;
    const int wid  = t >> 6;
    if (lane == 0) {
        #pragma unroll
        for (int j = 0; j < 4; ++j) partial[wid][j] = val[j];
    }
    __syncthreads();

    if (t < BQ) {
        int r = t;
        int j = r & 3;
        int w0 = (r >> 2) * 2;
        float a = fminf(partial[w0][j], partial[w0 + 1][j]);
        alphas[r] = (a > 1.f) ? 1.f : a;
    }
    __syncthreads();

    // z = c + alpha * (y - c), coalesced float4 stores
    #pragma unroll
    for (int k = 0; k < (BQ * NB) / BLOCK; ++k) {
        int pos = t + k * BLOCK;
        int row = pos >> 6;
        int n4i = pos & (NB - 1);
        float al = alphas[row];
        float4 m  = ymc[pos];
        float4 cv = c4s[n4i];
        float4 o;
        o.x = fmaf(al, m.x, cv.x);
        o.y = fmaf(al, m.y, cv.y);
        o.z = fmaf(al, m.z, cv.z);
        o.w = fmaf(al, m.w, cv.w);
        z4[base4 + pos] = o;
    }
}

extern "C" void kernel_launch(void* const* d_in, const int* in_sizes, int n_in,
                              void* d_out, int out_size, void* d_ws, size_t ws_size,
                              hipStream_t stream) {
    const float* y = (const float*)d_in[0];
    const float* A = (const float*)d_in[1];
    const float* b = (const float*)d_in[2];
    const float* c = (const float*)d_in[3];
    float* z = (float*)d_out;

    const int B = in_sizes[0] / N256;   // 4096
    const int grid = B / BQ;            // 256

    cel_kernel<<<grid, BLOCK, 0, stream>>>(y, A, b, c, z);
}